// Round 2
// baseline (400.547 us; speedup 1.0000x reference)
//
#include <hip/hip_runtime.h>

// CrossAttention: out = softmax((X1·Wq+bq)(X2·Wk+bk)^T/sqrt(D)) · (X2·Wv+bv)
// B=16, N1=N2=2048, D=512, L=256. Decomposed bf16 gemm_bt passes (m97
// 128x128-tile structure) + row softmax. Adaptive workspace layout:
//   Tier A (ws >= 225.5 MiB): full-batch S aliased over dead A1/A2.
//   Tier B (ws >= 145 MiB):   per-batch S (8 MiB), serialized per batch.

#define DIMD 512
#define LENL 256
#define BATCH 16
#define NQ 2048
#define NKV 2048

using bf16x8 = __attribute__((ext_vector_type(8))) __bf16;
using f32x4  = __attribute__((ext_vector_type(4))) float;
typedef unsigned short u16;

__device__ __forceinline__ u16 f2bf(float f) {
  union { float f; unsigned u; } x; x.f = f;
  unsigned r = (x.u + 0x7fffu + ((x.u >> 16) & 1u)) >> 16;
  return (u16)r;
}
__device__ __forceinline__ float bf2f(u16 b) {
  union { unsigned u; float f; } x; x.u = ((unsigned)b) << 16;
  return x.f;
}

// ---------------- fp32 -> bf16 elementwise (float4 vectorized) ----------------
__global__ __launch_bounds__(256) void k_cvt(const float* __restrict__ src,
                                             u16* __restrict__ dst, int n4) {
  int i = blockIdx.x * blockDim.x + threadIdx.x;
  int stride = gridDim.x * blockDim.x;
  for (; i < n4; i += stride) {
    float4 v = ((const float4*)src)[i];
    ushort4 o;
    o.x = f2bf(v.x); o.y = f2bf(v.y); o.z = f2bf(v.z); o.w = f2bf(v.w);
    ((ushort4*)dst)[i] = o;
  }
}

// ------------- weight transpose + cvt: W[K][N] f32 -> WT[N][K] bf16 -----------
__global__ __launch_bounds__(256) void k_transpose(const float* __restrict__ W,
                                                   u16* __restrict__ WT,
                                                   int K, int N) {
  __shared__ float t[32][33];
  int bx = blockIdx.x * 32;  // N direction
  int by = blockIdx.y * 32;  // K direction
  int tx = threadIdx.x, ty = threadIdx.y;  // (32,8)
#pragma unroll
  for (int i = 0; i < 4; i++)
    t[ty + 8 * i][tx] = W[(size_t)(by + ty + 8 * i) * N + (bx + tx)];
  __syncthreads();
#pragma unroll
  for (int i = 0; i < 4; i++)
    WT[(size_t)(bx + ty + 8 * i) * K + (by + tx)] = f2bf(t[tx][ty + 8 * i]);
}

// ---------------- async global->LDS 16B staging ----------------
__device__ __forceinline__ void gl_lds16(const void* g, void* l) {
  __builtin_amdgcn_global_load_lds(
      (const __attribute__((address_space(1))) void*)g,
      (__attribute__((address_space(3))) void*)l, 16, 0, 0);
}

// ---------------- gemm_bt: C[M][N] = A[M][K] * BT[N][K]^T (m97 structure) ----
// 128x128 tile, BK=32, 4 waves (2x2 of 64x64), mfma_f32_16x16x32_bf16.
// BIAS_MODE: 0 none, 1 bias[col], 2 bias[row]. OUT_BF16: 1 bf16 out, 0 f32 out.
template <int OUT_BF16, int BIAS_MODE>
__global__ __launch_bounds__(256) void k_gemm_bt(
    const u16* __restrict__ A, const u16* __restrict__ BT, void* __restrict__ Cv,
    const float* __restrict__ bias, int K, int lda, int ldb, int ldc,
    long sA, long sB, long sC, float scale) {
  __shared__ __align__(16) u16 As[128 * 32];
  __shared__ __align__(16) u16 Bs[128 * 32];
  const int tid  = threadIdx.x;
  const int lane = tid & 63;
  const int wid  = tid >> 6;
  const int wr   = wid >> 1, wc = wid & 1;
  const int brow = blockIdx.y * 128, bcol = blockIdx.x * 128;
  const long z   = blockIdx.z;
  const u16* Ab  = A + z * sA;
  const u16* Bb  = BT + z * sB;

  // staging: thread t -> row t/4 (and +64), 16B chunk (t%4) within 64B row
  const int srow = tid >> 2;
  const int scol = (tid & 3) * 8;
  const u16* ga0 = Ab + (long)(brow + srow) * lda + scol;
  const u16* ga1 = ga0 + 64L * lda;
  const u16* gb0 = Bb + (long)(bcol + srow) * ldb + scol;
  const u16* gb1 = gb0 + 64L * ldb;
  char* lA = (char*)As + tid * 16;
  char* lB = (char*)Bs + tid * 16;

  f32x4 acc[4][4];
  const f32x4 zero = {0.f, 0.f, 0.f, 0.f};
#pragma unroll
  for (int m = 0; m < 4; m++)
#pragma unroll
    for (int n = 0; n < 4; n++) acc[m][n] = zero;

  const int kg = (lane >> 4) * 16;  // byte offset of 8-elem k-group in 64B row
  const int fr = lane & 15;

  for (int k0 = 0; k0 < K; k0 += 32) {
    __syncthreads();
    gl_lds16(ga0 + k0, lA);
    gl_lds16(ga1 + k0, lA + 4096);
    gl_lds16(gb0 + k0, lB);
    gl_lds16(gb1 + k0, lB + 4096);
    __syncthreads();
    bf16x8 af[4], bfr[4];
#pragma unroll
    for (int m = 0; m < 4; m++)
      af[m] = *(const bf16x8*)((const char*)As + (wr * 64 + m * 16 + fr) * 64 + kg);
#pragma unroll
    for (int n = 0; n < 4; n++)
      bfr[n] = *(const bf16x8*)((const char*)Bs + (wc * 64 + n * 16 + fr) * 64 + kg);
#pragma unroll
    for (int m = 0; m < 4; m++)
#pragma unroll
      for (int n = 0; n < 4; n++)
        acc[m][n] = __builtin_amdgcn_mfma_f32_16x16x32_bf16(af[m], bfr[n],
                                                            acc[m][n], 0, 0, 0);
  }

  // epilogue: D layout col=lane&15, row=(lane>>4)*4+reg (m89-verified)
  const long zC = z * sC;
#pragma unroll
  for (int m = 0; m < 4; m++) {
    const int r0 = brow + wr * 64 + m * 16 + (lane >> 4) * 4;
#pragma unroll
    for (int n = 0; n < 4; n++) {
      const int c = bcol + wc * 64 + n * 16 + fr;
#pragma unroll
      for (int r = 0; r < 4; r++) {
        float v = acc[m][n][r] * scale;
        if (BIAS_MODE == 1) v += bias[c];
        if (BIAS_MODE == 2) v += bias[r0 + r];
        const long off = zC + (long)(r0 + r) * ldc + c;
        if (OUT_BF16) ((u16*)Cv)[off] = f2bf(v);
        else          ((float*)Cv)[off] = v;
      }
    }
  }
}

// ---------------- row softmax in place on bf16 rows of length 2048 ------------
__global__ __launch_bounds__(256) void k_softmax(u16* __restrict__ S) {
  const long row = blockIdx.x;
  u16* p = S + row * 2048;
  const int tid = threadIdx.x;
  int4 u = ((const int4*)p)[tid];
  unsigned w4[4] = {(unsigned)u.x, (unsigned)u.y, (unsigned)u.z, (unsigned)u.w};
  float v[8];
#pragma unroll
  for (int i = 0; i < 4; i++) {
    v[2 * i]     = bf2f((u16)(w4[i] & 0xffffu));
    v[2 * i + 1] = bf2f((u16)(w4[i] >> 16));
  }
  float m = v[0];
#pragma unroll
  for (int i = 1; i < 8; i++) m = fmaxf(m, v[i]);
#pragma unroll
  for (int off = 32; off >= 1; off >>= 1) m = fmaxf(m, __shfl_xor(m, off));
  __shared__ float redm[4], reds[4];
  const int wv = tid >> 6;
  if ((tid & 63) == 0) redm[wv] = m;
  __syncthreads();
  m = fmaxf(fmaxf(redm[0], redm[1]), fmaxf(redm[2], redm[3]));
  float s = 0.f, e[8];
#pragma unroll
  for (int i = 0; i < 8; i++) { e[i] = __expf(v[i] - m); s += e[i]; }
#pragma unroll
  for (int off = 32; off >= 1; off >>= 1) s += __shfl_xor(s, off);
  if ((tid & 63) == 0) reds[wv] = s;
  __syncthreads();
  s = (reds[0] + reds[1]) + (reds[2] + reds[3]);
  const float inv = 1.f / s;
  unsigned o[4];
#pragma unroll
  for (int i = 0; i < 4; i++)
    o[i] = (unsigned)f2bf(e[2 * i] * inv) | ((unsigned)f2bf(e[2 * i + 1] * inv) << 16);
  int4 ov; ov.x = (int)o[0]; ov.y = (int)o[1]; ov.z = (int)o[2]; ov.w = (int)o[3];
  ((int4*)p)[tid] = ov;
}

extern "C" void kernel_launch(void* const* d_in, const int* in_sizes, int n_in,
                              void* d_out, int out_size, void* d_ws, size_t ws_size,
                              hipStream_t stream) {
  (void)in_sizes; (void)n_in; (void)out_size;
  const float* in1 = (const float*)d_in[0];
  const float* in2 = (const float*)d_in[1];
  const float* Wq  = (const float*)d_in[2];
  const float* bq  = (const float*)d_in[3];
  const float* Wk  = (const float*)d_in[4];
  const float* bk  = (const float*)d_in[5];
  const float* Wv  = (const float*)d_in[6];
  const float* bv  = (const float*)d_in[7];
  float* out = (float*)d_out;

  const size_t MB = 1024ull * 1024ull;
  const size_t TIER_A = 225ull * MB;  // 235,929,600
  const size_t TIER_B = 145ull * MB;  // 152,043,520
  const bool fullS = ws_size >= TIER_A;
  if (!fullS && ws_size < TIER_B) return;  // loud failure: ws too small

  // layout: A1[0,32M), A2[32M,48M), S overlaps dead A1(+A2 in tier A);
  // live region (Q,K,VT,weights) starts at `base`.
  char* ws = (char*)d_ws;
  u16* A1  = (u16*)(ws + 0);
  u16* A2  = (u16*)(ws + 32 * MB);
  u16* S   = (u16*)(ws + 0);
  const size_t base = fullS ? 128 * MB : 48 * MB;
  u16* Q   = (u16*)(ws + base);
  u16* Kb  = (u16*)(ws + base + 32 * MB);
  u16* VT  = (u16*)(ws + base + 64 * MB);
  u16* WqT = (u16*)(ws + base + 96 * MB);
  u16* WkT = (u16*)(ws + base + 96 * MB + 524288);
  u16* WvT = (u16*)(ws + base + 96 * MB + 786432);

  // 1) inputs -> bf16
  k_cvt<<<2048, 256, 0, stream>>>(in1, A1, (int)((long)BATCH * NQ * DIMD / 4));
  k_cvt<<<2048, 256, 0, stream>>>(in2, A2, (int)((long)BATCH * NKV * LENL / 4));
  // 2) weight transposes -> bf16
  k_transpose<<<dim3(16, 16), dim3(32, 8), 0, stream>>>(Wq, WqT, DIMD, DIMD);
  k_transpose<<<dim3(16, 8),  dim3(32, 8), 0, stream>>>(Wk, WkT, LENL, DIMD);
  k_transpose<<<dim3(16, 8),  dim3(32, 8), 0, stream>>>(Wv, WvT, LENL, DIMD);

  // 3) Q = A1 @ WqT^T + bq   (M=32768, N=512, K=512)   [A1 dead after this]
  k_gemm_bt<1, 1><<<dim3(4, 256, 1), 256, 0, stream>>>(
      A1, WqT, Q, bq, 512, 512, 512, 512, 0, 0, 0, 1.f);
  // 4) K = A2 @ WkT^T + bk   (M=32768, N=512, K=256)
  k_gemm_bt<1, 1><<<dim3(4, 256, 1), 256, 0, stream>>>(
      A2, WkT, Kb, bk, 256, 256, 256, 512, 0, 0, 0, 1.f);
  // 5) VT[b] = WvT @ A2[b]^T + bv(row)  (M=512, N=2048, K=256, batched)
  //    [A2 dead after this]
  k_gemm_bt<1, 2><<<dim3(16, 4, 16), 256, 0, stream>>>(
      WvT, A2, VT, bv, 256, 256, 256, 2048,
      0L, (long)NKV * LENL, (long)DIMD * NKV, 1.f);

  const float qk_scale = 0.044194173824159216f;  // 1/sqrt(512)
  if (fullS) {
    // 6) S[b] = Q[b] @ Kb[b]^T / sqrt(D)  (M=2048, N=2048, K=512, batched)
    k_gemm_bt<1, 0><<<dim3(16, 16, 16), 256, 0, stream>>>(
        Q, Kb, S, nullptr, 512, 512, 512, 2048,
        (long)NQ * DIMD, (long)NKV * DIMD, (long)NQ * NKV, qk_scale);
    // 7) softmax rows in place
    k_softmax<<<BATCH * NQ, 256, 0, stream>>>(S);
    // 8) out[b] = P[b] @ VT[b]^T  (M=2048, N=512, K=2048, batched, f32 out)
    k_gemm_bt<0, 0><<<dim3(4, 16, 16), 256, 0, stream>>>(
        S, VT, out, nullptr, 2048, 2048, 2048, 512,
        (long)NQ * NKV, (long)DIMD * NKV, (long)NQ * DIMD, 1.f);
  } else {
    // per-batch: S is a single 8 MiB buffer, reused
    for (int b = 0; b < BATCH; b++) {
      const u16* Qb_ = Q + (long)b * NQ * DIMD;
      const u16* Kb_ = Kb + (long)b * NKV * DIMD;
      const u16* VTb = VT + (long)b * DIMD * NKV;
      float* ob = out + (long)b * NQ * DIMD;
      k_gemm_bt<1, 0><<<dim3(16, 16, 1), 256, 0, stream>>>(
          Qb_, Kb_, S, nullptr, 512, 512, 512, 2048, 0, 0, 0, qk_scale);
      k_softmax<<<NQ, 256, 0, stream>>>(S);
      k_gemm_bt<0, 0><<<dim3(4, 16, 1), 256, 0, stream>>>(
          S, VTb, ob, nullptr, 2048, 2048, 2048, 512, 0, 0, 0, 1.f);
    }
  }
}

// Round 3
// 324.168 us; speedup vs baseline: 1.2356x; 1.2356x over previous
//
#include <hip/hip_runtime.h>

// CrossAttention B=16, N1=N2=2048, D=512, L=256.
// bf16 gemm_bt (128x128 tile, 2-phase double-buffered LDS, XCD swizzle) with
// softmax fused into the QK epilogue (unnormalized exp + row-sum partials);
// PV epilogue applies 1/rowsum. Workspace: ~163 MiB.

#define DIMD 512
#define LENL 256
#define BATCH 16
#define NQ 2048
#define NKV 2048

using bf16x8 = __attribute__((ext_vector_type(8))) __bf16;
using f32x4  = __attribute__((ext_vector_type(4))) float;
typedef unsigned short u16;

__device__ __forceinline__ u16 f2bf(float f) {
  union { float f; unsigned u; } x; x.f = f;
  return (u16)((x.u + 0x7fffu + ((x.u >> 16) & 1u)) >> 16);
}
__device__ __forceinline__ float bf2f(u16 b) {
  union { unsigned u; float f; } x; x.u = ((unsigned)b) << 16;
  return x.f;
}

// ---------------- fp32 -> bf16 elementwise (float4 vectorized) ----------------
__global__ __launch_bounds__(256) void k_cvt(const float* __restrict__ src,
                                             u16* __restrict__ dst, int n4) {
  int i = blockIdx.x * blockDim.x + threadIdx.x;
  int stride = gridDim.x * blockDim.x;
  for (; i < n4; i += stride) {
    float4 v = ((const float4*)src)[i];
    ushort4 o;
    o.x = f2bf(v.x); o.y = f2bf(v.y); o.z = f2bf(v.z); o.w = f2bf(v.w);
    ((ushort4*)dst)[i] = o;
  }
}

// ------------- weight transpose + cvt: W[K][N] f32 -> WT[N][K] bf16 -----------
__global__ __launch_bounds__(256) void k_transpose(const float* __restrict__ W,
                                                   u16* __restrict__ WT,
                                                   int K, int N) {
  __shared__ float t[32][33];
  int bx = blockIdx.x * 32;
  int by = blockIdx.y * 32;
  int tx = threadIdx.x, ty = threadIdx.y;  // (32,8)
#pragma unroll
  for (int i = 0; i < 4; i++)
    t[ty + 8 * i][tx] = W[(size_t)(by + ty + 8 * i) * N + (bx + tx)];
  __syncthreads();
#pragma unroll
  for (int i = 0; i < 4; i++)
    WT[(size_t)(bx + ty + 8 * i) * K + (by + tx)] = f2bf(t[tx][ty + 8 * i]);
}

// ---------------- async global->LDS 16B staging ----------------
__device__ __forceinline__ void gl_lds16(const void* g, void* l) {
  __builtin_amdgcn_global_load_lds(
      (const __attribute__((address_space(1))) void*)g,
      (__attribute__((address_space(3))) void*)l, 16, 0, 0);
}

// ---------------- bijective XCD-aware block swizzle (T1, m204 form) -----------
__device__ __forceinline__ void xcd_swz(int& bx, int& by, int& bz) {
  const int nx = gridDim.x, ny = gridDim.y, nz = gridDim.z;
  const long nwg = (long)nx * ny * nz;
  if (nwg & 7) return;  // only when divisible by 8 XCDs
  long lin = (long)bx + (long)nx * ((long)by + (long)ny * bz);
  const long q = nwg >> 3;
  const long nl = (lin & 7) * q + (lin >> 3);
  bx = (int)(nl % nx);
  long r2 = nl / nx;
  by = (int)(r2 % ny);
  bz = (int)(r2 / ny);
}

// ---------------- gemm_bt: C[M][N] = A[M][K] * BT[N][K]^T ---------------------
// 128x128 tile, BK=32, 2-phase double-buffered LDS (T3-minimum), 4 waves.
// OUT_BF16: 1 bf16 out, 0 f32. BIAS_MODE: 0 none, 1 bias[col], 2 bias[row].
// FUSE: 0 none; 1 = C=exp(v) bf16 + row-sum partials; 2 = v *= 1/rowsum.
template <int OUT_BF16, int BIAS_MODE, int FUSE>
__global__ __launch_bounds__(256) void k_gemm_bt(
    const u16* __restrict__ A, const u16* __restrict__ BT, void* __restrict__ Cv,
    const float* __restrict__ bias, float* __restrict__ fpart,
    const float* __restrict__ finv,
    int K, int lda, int ldb, int ldc, long sA, long sB, long sC, float scale) {
  __shared__ __align__(16) char lds[32768];  // A dbuf [0,16K), B dbuf [16K,32K)
  __shared__ float part[128];
  __shared__ float invs[128];

  int bxi = blockIdx.x, byi = blockIdx.y, bzi = blockIdx.z;
  xcd_swz(bxi, byi, bzi);
  const int tid = threadIdx.x, lane = tid & 63, wid = tid >> 6;
  const int wr = wid >> 1, wc = wid & 1;
  const int brow = byi * 128, bcol = bxi * 128;
  const long z = bzi;

  if (FUSE == 2 && tid < 128) invs[tid] = finv[z * 2048 + brow + tid];

  // staging: thread t -> row t/4 (and +64), 16B chunk (t%4) within 64B row
  const int srow = tid >> 2, scol = (tid & 3) * 8;
  const u16* ga0 = A + z * sA + (long)(brow + srow) * lda + scol;
  const u16* ga1 = ga0 + 64L * lda;
  const u16* gb0 = BT + z * sB + (long)(bcol + srow) * ldb + scol;
  const u16* gb1 = gb0 + 64L * ldb;
  const int toff = tid * 16;

  f32x4 acc[4][4];
  const f32x4 zero = {0.f, 0.f, 0.f, 0.f};
#pragma unroll
  for (int m = 0; m < 4; m++)
#pragma unroll
    for (int n = 0; n < 4; n++) acc[m][n] = zero;

  // prologue: stage tile 0 into buffer 0
  gl_lds16(ga0, lds + toff);
  gl_lds16(ga1, lds + 4096 + toff);
  gl_lds16(gb0, lds + 16384 + toff);
  gl_lds16(gb1, lds + 16384 + 4096 + toff);
  __syncthreads();  // vmcnt(0) drain + barrier

  const int kg = (lane >> 4) * 16;  // byte offset of 8-elem k-group in 64B row
  const int fr = lane & 15;
  const int nt = K / 32;

  for (int t = 0; t < nt; t++) {
    const int cur = t & 1, nxt = cur ^ 1;
    if (t + 1 < nt) {  // issue next tile's loads before consuming current
      const int k1 = (t + 1) * 32;
      gl_lds16(ga0 + k1, lds + nxt * 8192 + toff);
      gl_lds16(ga1 + k1, lds + nxt * 8192 + 4096 + toff);
      gl_lds16(gb0 + k1, lds + 16384 + nxt * 8192 + toff);
      gl_lds16(gb1 + k1, lds + 16384 + nxt * 8192 + 4096 + toff);
    }
    const char* bA = lds + cur * 8192;
    const char* bB = lds + 16384 + cur * 8192;
    bf16x8 af[4], bfr[4];
#pragma unroll
    for (int m = 0; m < 4; m++)
      af[m] = *(const bf16x8*)(bA + (wr * 64 + m * 16 + fr) * 64 + kg);
#pragma unroll
    for (int n = 0; n < 4; n++)
      bfr[n] = *(const bf16x8*)(bB + (wc * 64 + n * 16 + fr) * 64 + kg);
#pragma unroll
    for (int m = 0; m < 4; m++)
#pragma unroll
      for (int n = 0; n < 4; n++)
        acc[m][n] = __builtin_amdgcn_mfma_f32_16x16x32_bf16(af[m], bfr[n],
                                                            acc[m][n], 0, 0, 0);
    __syncthreads();  // drains next-tile vmcnt + protects buffer reuse
  }

  if (FUSE == 1) {
    if (tid < 128) part[tid] = 0.f;
    __syncthreads();
  }

  // epilogue: D layout col=lane&15, row=(lane>>4)*4+reg (m89-verified)
  const long zC = z * sC;
#pragma unroll
  for (int m = 0; m < 4; m++) {
    const int r0 = brow + wr * 64 + m * 16 + (lane >> 4) * 4;
    float s4[4] = {0.f, 0.f, 0.f, 0.f};
#pragma unroll
    for (int n = 0; n < 4; n++) {
      const int c = bcol + wc * 64 + n * 16 + fr;
#pragma unroll
      for (int r = 0; r < 4; r++) {
        float v = acc[m][n][r] * scale;
        if (BIAS_MODE == 1) v += bias[c];
        if (BIAS_MODE == 2) v += bias[r0 + r];
        if (FUSE == 2) v *= invs[r0 + r - brow];
        const long off = zC + (long)(r0 + r) * ldc + c;
        if (FUSE == 1) {
          float ef = __expf(fminf(v, 30.f));
          u16 eb = f2bf(ef);
          ((u16*)Cv)[off] = eb;
          s4[r] += bf2f(eb);  // sum the rounded values PV will actually read
        } else if (OUT_BF16) {
          ((u16*)Cv)[off] = f2bf(v);
        } else {
          ((float*)Cv)[off] = v;
        }
      }
    }
    if (FUSE == 1) {
#pragma unroll
      for (int r = 0; r < 4; r++) {
        float s = s4[r];
        s += __shfl_xor(s, 1); s += __shfl_xor(s, 2);
        s += __shfl_xor(s, 4); s += __shfl_xor(s, 8);
        if (fr == 0) atomicAdd(&part[r0 - brow + r], s);
      }
    }
  }
  if (FUSE == 1) {
    __syncthreads();
    if (tid < 128)
      fpart[((long)z * 16 + bxi) * 2048 + brow + tid] = part[tid];
  }
}

// ---------- invsum: inv[i] = 1 / sum_j partials[j][i] (16 col-tile slots) -----
__global__ __launch_bounds__(256) void k_invsum(const float* __restrict__ part,
                                                float* __restrict__ inv) {
  int i = blockIdx.x * blockDim.x + threadIdx.x;  // over nrows
  long z = i >> 11;
  int row = i & 2047;
  float s = 0.f;
#pragma unroll
  for (int j = 0; j < 16; j++) s += part[(((z << 4) + j) << 11) + row];
  inv[i] = 1.f / s;
}

extern "C" void kernel_launch(void* const* d_in, const int* in_sizes, int n_in,
                              void* d_out, int out_size, void* d_ws, size_t ws_size,
                              hipStream_t stream) {
  (void)in_sizes; (void)n_in; (void)out_size;
  const float* in1 = (const float*)d_in[0];
  const float* in2 = (const float*)d_in[1];
  const float* Wq  = (const float*)d_in[2];
  const float* bq  = (const float*)d_in[3];
  const float* Wk  = (const float*)d_in[4];
  const float* bk  = (const float*)d_in[5];
  const float* Wv  = (const float*)d_in[6];
  const float* bv  = (const float*)d_in[7];
  float* out = (float*)d_out;

  const size_t MB = 1024ull * 1024ull;
  if (ws_size < 172 * MB) return;  // need ~163.2 MiB (known ws >= 225 MiB)

  // layout (MiB): S-chunk [0,64) overlaps A1[0,32)+A2[32,48); Q 64; K 96;
  // VT 128; weights 160; partials 161; invsum 162.25
  char* ws = (char*)d_ws;
  u16* A1   = (u16*)(ws + 0);
  u16* A2   = (u16*)(ws + 32 * MB);
  u16* S    = (u16*)(ws + 0);           // 8 batches x 8 MiB, reused per chunk
  u16* Q    = (u16*)(ws + 64 * MB);
  u16* Kb   = (u16*)(ws + 96 * MB);
  u16* VT   = (u16*)(ws + 128 * MB);
  u16* WqT  = (u16*)(ws + 160 * MB);
  u16* WkT  = (u16*)(ws + 160 * MB + 524288);
  u16* WvT  = (u16*)(ws + 160 * MB + 786432);
  float* Pt = (float*)(ws + 161 * MB);          // partials: 8 x 16 x 2048 f32
  float* Iv = (float*)(ws + 162 * MB + 262144); // invsum: 8 x 2048 f32

  // 1) inputs -> bf16
  k_cvt<<<2048, 256, 0, stream>>>(in1, A1, (int)((long)BATCH * NQ * DIMD / 4));
  k_cvt<<<2048, 256, 0, stream>>>(in2, A2, (int)((long)BATCH * NKV * LENL / 4));
  // 2) weight transposes -> bf16
  k_transpose<<<dim3(16, 16), dim3(32, 8), 0, stream>>>(Wq, WqT, DIMD, DIMD);
  k_transpose<<<dim3(16, 8),  dim3(32, 8), 0, stream>>>(Wk, WkT, LENL, DIMD);
  k_transpose<<<dim3(16, 8),  dim3(32, 8), 0, stream>>>(Wv, WvT, LENL, DIMD);

  // 3) projections
  k_gemm_bt<1, 1, 0><<<dim3(4, 256, 1), 256, 0, stream>>>(
      A1, WqT, Q, bq, nullptr, nullptr, 512, 512, 512, 512, 0, 0, 0, 1.f);
  k_gemm_bt<1, 1, 0><<<dim3(4, 256, 1), 256, 0, stream>>>(
      A2, WkT, Kb, bk, nullptr, nullptr, 256, 256, 256, 512, 0, 0, 0, 1.f);
  k_gemm_bt<1, 2, 0><<<dim3(16, 4, 16), 256, 0, stream>>>(
      WvT, A2, VT, bv, nullptr, nullptr, 256, 256, 256, 2048,
      0L, (long)NKV * LENL, (long)DIMD * NKV, 1.f);

  const float qk_scale = 0.044194173824159216f;  // 1/sqrt(512)
  for (int c = 0; c < 2; c++) {
    const int zb = c * 8;
    // 4) S = exp(Q K^T / sqrt(D)) (bf16, unnormalized) + row-sum partials
    k_gemm_bt<1, 0, 1><<<dim3(16, 16, 8), 256, 0, stream>>>(
        Q + (long)zb * NQ * DIMD, Kb + (long)zb * NKV * DIMD, S, nullptr,
        Pt, nullptr, 512, 512, 512, 2048,
        (long)NQ * DIMD, (long)NKV * DIMD, (long)NQ * NKV, qk_scale);
    // 5) inv row sums (8 x 2048 rows)
    k_invsum<<<64, 256, 0, stream>>>(Pt, Iv);
    // 6) out = (S~ @ VT^T) * invsum   (f32 out)
    k_gemm_bt<0, 0, 2><<<dim3(4, 16, 8), 256, 0, stream>>>(
        S, VT + (long)zb * DIMD * NKV, out + (long)zb * NQ * DIMD, nullptr,
        nullptr, Iv, 2048, 2048, 2048, 512,
        (long)NQ * NKV, (long)DIMD * NKV, (long)NQ * DIMD, 1.f);
  }
}

// Round 4
// 310.653 us; speedup vs baseline: 1.2894x; 1.0435x over previous
//
#include <hip/hip_runtime.h>

// CrossAttention B=16, N1=N2=2048, D=512, L=256.
// All GEMMs on a 256x256-tile, BK=64, 8-wave, 8-phase counted-vmcnt kernel
// (T2 swizzle + T3/T4 schedule + T5 setprio, per the verified m201 template).
// Softmax fused into QK epilogue (unnormalized exp + row-sum partials);
// PV epilogue applies 1/rowsum. Workspace: ~163 MiB.

#define DIMD 512
#define LENL 256
#define BATCH 16
#define NQ 2048
#define NKV 2048

using bf16x8 = __attribute__((ext_vector_type(8))) __bf16;
using f32x4  = __attribute__((ext_vector_type(4))) float;
typedef unsigned short u16;

__device__ __forceinline__ u16 f2bf(float f) {
  union { float f; unsigned u; } x; x.f = f;
  return (u16)((x.u + 0x7fffu + ((x.u >> 16) & 1u)) >> 16);
}
__device__ __forceinline__ float bf2f(u16 b) {
  union { unsigned u; float f; } x; x.u = ((unsigned)b) << 16;
  return x.f;
}

// ---------------- fp32 -> bf16 elementwise (float4 vectorized) ----------------
__global__ __launch_bounds__(256) void k_cvt(const float* __restrict__ src,
                                             u16* __restrict__ dst, int n4) {
  int i = blockIdx.x * blockDim.x + threadIdx.x;
  int stride = gridDim.x * blockDim.x;
  for (; i < n4; i += stride) {
    float4 v = ((const float4*)src)[i];
    ushort4 o;
    o.x = f2bf(v.x); o.y = f2bf(v.y); o.z = f2bf(v.z); o.w = f2bf(v.w);
    ((ushort4*)dst)[i] = o;
  }
}

// ------------- weight transpose + cvt: W[K][N] f32 -> WT[N][K] bf16 -----------
__global__ __launch_bounds__(256) void k_transpose(const float* __restrict__ W,
                                                   u16* __restrict__ WT,
                                                   int K, int N) {
  __shared__ float t[32][33];
  int bx = blockIdx.x * 32;
  int by = blockIdx.y * 32;
  int tx = threadIdx.x, ty = threadIdx.y;  // (32,8)
#pragma unroll
  for (int i = 0; i < 4; i++)
    t[ty + 8 * i][tx] = W[(size_t)(by + ty + 8 * i) * N + (bx + tx)];
  __syncthreads();
#pragma unroll
  for (int i = 0; i < 4; i++)
    WT[(size_t)(bx + ty + 8 * i) * K + (by + tx)] = f2bf(t[tx][ty + 8 * i]);
}

// ---------------- async global->LDS 16B staging ----------------
__device__ __forceinline__ void gl_lds16(const void* g, void* l) {
  __builtin_amdgcn_global_load_lds(
      (const __attribute__((address_space(1))) void*)g,
      (__attribute__((address_space(3))) void*)l, 16, 0, 0);
}

// ---------------- bijective XCD-aware block swizzle (T1, m204 form) -----------
__device__ __forceinline__ void xcd_swz(int& bx, int& by, int& bz) {
  const int nx = gridDim.x, ny = gridDim.y, nz = gridDim.z;
  const long nwg = (long)nx * ny * nz;
  if (nwg & 7) return;
  long lin = (long)bx + (long)nx * ((long)by + (long)ny * bz);
  const long q = nwg >> 3;
  const long nl = (lin & 7) * q + (lin >> 3);
  bx = (int)(nl % nx);
  long r2 = nl / nx;
  by = (int)(r2 % ny);
  bz = (int)(r2 / ny);
}

// =============== 256x256 8-phase gemm_bt: C = A[M][K] * BT[N][K]^T ============
// 8 waves (2M x 4N), per-wave 128x64 C. LDS: A dbuf [0,64K), B dbuf [64K,128K),
// part/invs [128K,+1K). Swizzle: slot ^= row&7 on global src + ds_read addr.
// FUSE: 0 none; 1 = exp(v) bf16 + row-sum partials; 2 = v *= finv[row].
#define SA(p, h, l, T) \
  gl_lds16(gA + (long)((h) * 128 + (l) * 64) * lda + (T) * 64, \
           dA + (p) * 32768 + (h) * 16384 + (l) * 8192)
#define SB(p, h, l, T) \
  gl_lds16(gB + (long)((h) * 128 + (l) * 64) * ldb + (T) * 64, \
           dB + (p) * 32768 + (h) * 16384 + (l) * 8192)
#define RD_A(p, mh) { _Pragma("unroll") for (int m = 0; m < 4; m++) { \
    afr[m][0] = *(const bf16x8*)(lds + (p) * 32768 + aoffb + ((mh) * 64 + m * 16) * 128 + sb0); \
    afr[m][1] = *(const bf16x8*)(lds + (p) * 32768 + aoffb + ((mh) * 64 + m * 16) * 128 + sb1); } }
#define RD_B(p, nh, BF) { _Pragma("unroll") for (int n = 0; n < 2; n++) { \
    BF[n][0] = *(const bf16x8*)(lds + (p) * 32768 + boffb + (((nh) * 2 + n) * 16) * 128 + sb0); \
    BF[n][1] = *(const bf16x8*)(lds + (p) * 32768 + boffb + (((nh) * 2 + n) * 16) * 128 + sb1); } }
#define MFMA_QUAD(mh, nh, BF) { \
  _Pragma("unroll") for (int m = 0; m < 4; m++) \
  _Pragma("unroll") for (int n = 0; n < 2; n++) \
  _Pragma("unroll") for (int kk = 0; kk < 2; kk++) \
    acc[(mh) * 4 + m][(nh) * 2 + n] = __builtin_amdgcn_mfma_f32_16x16x32_bf16( \
        afr[m][kk], BF[n][kk], acc[(mh) * 4 + m][(nh) * 2 + n], 0, 0, 0); }
#define BAR_MFMA_OPEN() \
  __builtin_amdgcn_sched_barrier(0); \
  __builtin_amdgcn_s_barrier(); \
  asm volatile("s_waitcnt lgkmcnt(0)" ::: "memory"); \
  __builtin_amdgcn_sched_barrier(0); \
  __builtin_amdgcn_s_setprio(1)
#define PH_CLOSE() \
  __builtin_amdgcn_s_setprio(0); \
  __builtin_amdgcn_sched_barrier(0); \
  __builtin_amdgcn_s_barrier(); \
  __builtin_amdgcn_sched_barrier(0)
#define PH_CLOSE_VM(N) \
  __builtin_amdgcn_s_setprio(0); \
  asm volatile("s_waitcnt vmcnt(" #N ")" ::: "memory"); \
  __builtin_amdgcn_sched_barrier(0); \
  __builtin_amdgcn_s_barrier(); \
  __builtin_amdgcn_sched_barrier(0)

template <int OUT_BF16, int BIAS_MODE, int FUSE>
__global__ __launch_bounds__(512, 2) void k_gemm256(
    const u16* __restrict__ A, const u16* __restrict__ BT,
    void* __restrict__ Cv, const float* __restrict__ bias,
    float* __restrict__ fpart, const float* __restrict__ finv,
    int K, int lda, int ldb, int ldc, long sA, long sB, long sC, float scale) {
  __shared__ __align__(16) char lds[132096];
  float* part = (float*)(lds + 131072);

  int bxi = blockIdx.x, byi = blockIdx.y, bzi = blockIdx.z;
  xcd_swz(bxi, byi, bzi);
  const int tid = threadIdx.x, lane = tid & 63, wid = tid >> 6;
  const int wr = wid >> 2, wc = wid & 3;
  const int fr = lane & 15, kq = lane >> 4, fr7 = fr & 7;
  const int brow = byi * 256, bcol = bxi * 256;
  const long z = bzi;

  if (FUSE == 2 && tid < 256) part[tid] = finv[z * 2048 + brow + tid];

  // staging: thread t stages one 16B chunk per load; dest linear, src col
  // pre-swizzled (rule 21): col16 = (t&7) ^ ((t/8)&7)
  const int srow = tid >> 3;
  const int sslot = (tid & 7) ^ (srow & 7);
  const u16* gA = A + z * sA + (long)(brow + srow) * lda + sslot * 8;
  const u16* gB = BT + z * sB + (long)(bcol + srow) * ldb + sslot * 8;
  char* dA = lds + tid * 16;
  char* dB = lds + 65536 + tid * 16;

  // read-side bases; slot byte = ((kk*4+kq)^fr7)*16
  const int aoffb = (wr * 128 + fr) * 128;
  const int boffb = 65536 + (wc * 64 + fr) * 128;
  const int sb0 = (kq ^ fr7) * 16;
  const int sb1 = ((4 + kq) ^ fr7) * 16;

  f32x4 acc[8][4];
  const f32x4 zero = {0.f, 0.f, 0.f, 0.f};
#pragma unroll
  for (int m = 0; m < 8; m++)
#pragma unroll
    for (int n = 0; n < 4; n++) acc[m][n] = zero;

  // prologue: tile0 full -> buf0 (8 loads), tile1 B halves -> buf1 (4 loads)
  SA(0, 0, 0, 0); SA(0, 0, 1, 0); SA(0, 1, 0, 0); SA(0, 1, 1, 0);
  SB(0, 0, 0, 0); SB(0, 0, 1, 0); SB(0, 1, 0, 0); SB(0, 1, 1, 0);
  SB(1, 0, 0, 1); SB(1, 0, 1, 1); SB(1, 1, 0, 1); SB(1, 1, 1, 1);
  asm volatile("s_waitcnt vmcnt(4)" ::: "memory");
  __builtin_amdgcn_sched_barrier(0);
  __builtin_amdgcn_s_barrier();

  bf16x8 afr[4][2], bf0[2][2], bf1[2][2];
  const int iters = K >> 7;  // K / 128 (2 K-tiles per iteration)

  for (int i = 0; i < iters; i++) {
    const int t1 = 2 * i + 1, p0 = 2 * i + 2, p1 = 2 * i + 3;
    const bool more = (i + 1 < iters);
    // ph1: tile t0 (buf0) quad(0,0); stage A[t1]h0 -> buf1
    RD_A(0, 0); RD_B(0, 0, bf0);
    SA(1, 0, 0, t1); SA(1, 0, 1, t1);
    BAR_MFMA_OPEN(); MFMA_QUAD(0, 0, bf0); PH_CLOSE();
    // ph2: quad(0,1); stage A[t1]h1
    RD_B(0, 1, bf1);
    SA(1, 1, 0, t1); SA(1, 1, 1, t1);
    BAR_MFMA_OPEN(); MFMA_QUAD(0, 1, bf1); PH_CLOSE();
    // ph3: quad(1,0); stage B[p0]h0 -> buf0 (buf0-B reads done after ph2)
    RD_A(0, 1);
    if (more) { SB(0, 0, 0, p0); SB(0, 0, 1, p0); }
    BAR_MFMA_OPEN(); MFMA_QUAD(1, 0, bf0); PH_CLOSE();
    // ph4: quad(1,1); stage B[p0]h1; counted wait -> t1 fully landed
    if (more) { SB(0, 1, 0, p0); SB(0, 1, 1, p0); }
    BAR_MFMA_OPEN(); MFMA_QUAD(1, 1, bf1);
    if (more) { PH_CLOSE_VM(4); } else { PH_CLOSE_VM(0); }
    // ph5: tile t1 (buf1) quad(0,0); stage A[p0]h0 (buf0-A reads done ph3)
    RD_A(1, 0); RD_B(1, 0, bf0);
    if (more) { SA(0, 0, 0, p0); SA(0, 0, 1, p0); }
    BAR_MFMA_OPEN(); MFMA_QUAD(0, 0, bf0); PH_CLOSE();
    // ph6: quad(0,1); stage A[p0]h1
    RD_B(1, 1, bf1);
    if (more) { SA(0, 1, 0, p0); SA(0, 1, 1, p0); }
    BAR_MFMA_OPEN(); MFMA_QUAD(0, 1, bf1); PH_CLOSE();
    // ph7: quad(1,0); stage B[p1]h0 -> buf1 (buf1-B reads done after ph6)
    RD_A(1, 1);
    if (more) { SB(1, 0, 0, p1); SB(1, 0, 1, p1); }
    BAR_MFMA_OPEN(); MFMA_QUAD(1, 0, bf0); PH_CLOSE();
    // ph8: quad(1,1); stage B[p1]h1; counted wait -> p0 fully landed
    if (more) { SB(1, 1, 0, p1); SB(1, 1, 1, p1); }
    BAR_MFMA_OPEN(); MFMA_QUAD(1, 1, bf1);
    if (more) { PH_CLOSE_VM(4); } else { PH_CLOSE_VM(0); }
  }

  if (FUSE == 1) {
    if (tid < 256) part[tid] = 0.f;
    __syncthreads();
  }

  // epilogue: D layout col=lane&15, row=kq*4+reg (m89-verified)
  const long zC = z * sC;
#pragma unroll
  for (int mi = 0; mi < 8; mi++) {
    const int r0 = brow + wr * 128 + mi * 16 + kq * 4;
    float s4[4] = {0.f, 0.f, 0.f, 0.f};
#pragma unroll
    for (int n = 0; n < 4; n++) {
      const int c = bcol + wc * 64 + n * 16 + fr;
#pragma unroll
      for (int r = 0; r < 4; r++) {
        float v = acc[mi][n][r] * scale;
        if (BIAS_MODE == 1) v += bias[c];
        if (BIAS_MODE == 2) v += bias[r0 + r];
        if (FUSE == 2) v *= part[r0 + r - brow];
        const long off = zC + (long)(r0 + r) * ldc + c;
        if (FUSE == 1) {
          float ef = __expf(fminf(v, 30.f));
          u16 eb = f2bf(ef);
          ((u16*)Cv)[off] = eb;
          s4[r] += bf2f(eb);  // sum the rounded values PV will read
        } else if (OUT_BF16) {
          ((u16*)Cv)[off] = f2bf(v);
        } else {
          ((float*)Cv)[off] = v;
        }
      }
    }
    if (FUSE == 1) {
#pragma unroll
      for (int r = 0; r < 4; r++) {
        float s = s4[r];
        s += __shfl_xor(s, 1); s += __shfl_xor(s, 2);
        s += __shfl_xor(s, 4); s += __shfl_xor(s, 8);
        if (fr == 0) atomicAdd(&part[r0 - brow + r], s);
      }
    }
  }
  if (FUSE == 1) {
    __syncthreads();
    if (tid < 256)
      fpart[((long)z * gridDim.x + bxi) * 2048 + brow + tid] = part[tid];
  }
}

// ---------- invsum: inv[i] = 1 / sum_j partials[j][i] (8 col-tile slots) ------
__global__ __launch_bounds__(256) void k_invsum(const float* __restrict__ part,
                                                float* __restrict__ inv) {
  int i = blockIdx.x * blockDim.x + threadIdx.x;
  long z = i >> 11;
  int row = i & 2047;
  float s = 0.f;
#pragma unroll
  for (int j = 0; j < 8; j++) s += part[(((z << 3) + j) << 11) + row];
  inv[i] = 1.f / s;
}

extern "C" void kernel_launch(void* const* d_in, const int* in_sizes, int n_in,
                              void* d_out, int out_size, void* d_ws, size_t ws_size,
                              hipStream_t stream) {
  (void)in_sizes; (void)n_in; (void)out_size;
  const float* in1 = (const float*)d_in[0];
  const float* in2 = (const float*)d_in[1];
  const float* Wq  = (const float*)d_in[2];
  const float* bq  = (const float*)d_in[3];
  const float* Wk  = (const float*)d_in[4];
  const float* bk  = (const float*)d_in[5];
  const float* Wv  = (const float*)d_in[6];
  const float* bv  = (const float*)d_in[7];
  float* out = (float*)d_out;

  const size_t MB = 1024ull * 1024ull;
  if (ws_size < 172 * MB) return;

  char* ws = (char*)d_ws;
  u16* A1   = (u16*)(ws + 0);
  u16* A2   = (u16*)(ws + 32 * MB);
  u16* S    = (u16*)(ws + 0);           // 8 batches x 8 MiB, reused per chunk
  u16* Q    = (u16*)(ws + 64 * MB);
  u16* Kb   = (u16*)(ws + 96 * MB);
  u16* VT   = (u16*)(ws + 128 * MB);
  u16* WqT  = (u16*)(ws + 160 * MB);
  u16* WkT  = (u16*)(ws + 160 * MB + 524288);
  u16* WvT  = (u16*)(ws + 160 * MB + 786432);
  float* Pt = (float*)(ws + 161 * MB);          // partials: 8 x 8 x 2048 f32
  float* Iv = (float*)(ws + 162 * MB + 262144); // invsum: 8 x 2048 f32

  k_cvt<<<2048, 256, 0, stream>>>(in1, A1, (int)((long)BATCH * NQ * DIMD / 4));
  k_cvt<<<2048, 256, 0, stream>>>(in2, A2, (int)((long)BATCH * NKV * LENL / 4));
  k_transpose<<<dim3(16, 16), dim3(32, 8), 0, stream>>>(Wq, WqT, DIMD, DIMD);
  k_transpose<<<dim3(16, 8),  dim3(32, 8), 0, stream>>>(Wk, WkT, LENL, DIMD);
  k_transpose<<<dim3(16, 8),  dim3(32, 8), 0, stream>>>(Wv, WvT, LENL, DIMD);

  // projections (256² 8-phase)
  k_gemm256<1, 1, 0><<<dim3(2, 128, 1), 512, 0, stream>>>(
      A1, WqT, Q, bq, nullptr, nullptr, 512, 512, 512, 512, 0, 0, 0, 1.f);
  k_gemm256<1, 1, 0><<<dim3(2, 128, 1), 512, 0, stream>>>(
      A2, WkT, Kb, bk, nullptr, nullptr, 256, 256, 256, 512, 0, 0, 0, 1.f);
  k_gemm256<1, 2, 0><<<dim3(8, 2, 16), 512, 0, stream>>>(
      WvT, A2, VT, bv, nullptr, nullptr, 256, 256, 256, 2048,
      0L, (long)NKV * LENL, (long)DIMD * NKV, 1.f);

  const float qk_scale = 0.044194173824159216f;  // 1/sqrt(512)
  for (int c = 0; c < 2; c++) {
    const int zb = c * 8;
    // S = exp(Q K^T / sqrt(D)) (bf16, unnormalized) + row-sum partials
    k_gemm256<1, 0, 1><<<dim3(8, 8, 8), 512, 0, stream>>>(
        Q + (long)zb * NQ * DIMD, Kb + (long)zb * NKV * DIMD, S, nullptr,
        Pt, nullptr, 512, 512, 512, 2048,
        (long)NQ * DIMD, (long)NKV * DIMD, (long)NQ * NKV, qk_scale);
    k_invsum<<<64, 256, 0, stream>>>(Pt, Iv);
    // out = (S~ @ VT^T) * invsum   (f32 out)
    k_gemm256<0, 0, 2><<<dim3(2, 8, 8), 512, 0, stream>>>(
        S, VT + (long)zb * DIMD * NKV, out + (long)zb * NQ * DIMD, nullptr,
        nullptr, Iv, 2048, 2048, 2048, 512,
        (long)NQ * NKV, (long)DIMD * NKV, (long)NQ * DIMD, 1.f);
  }
}

// Round 6
// 282.385 us; speedup vs baseline: 1.4184x; 1.1001x over previous
//
#include <hip/hip_runtime.h>

// CrossAttention B=16, N1=N2=2048, D=512, L=256.
// All GEMMs on a 256-row-tile, BK=64, 8-wave, counted-vmcnt kernel
// (T2 swizzle + T3/T4 schedule + T5 setprio). BNH=2: 256x256 tile, 8-phase.
// BNH=1: 256x128 tile, 4-phase (for PV whose N=512 needs more blocks).
// Softmax fused into QK epilogue (unnormalized exp + row-sum partials);
// PV epilogue applies 1/rowsum. Workspace: ~163 MiB.
// [Round 6 = round 5 resubmitted: prior bench died to an infra error
//  (UnresponsiveContainer) with no kernel verdict.]

#define DIMD 512
#define LENL 256
#define BATCH 16
#define NQ 2048
#define NKV 2048

using bf16x8 = __attribute__((ext_vector_type(8))) __bf16;
using f32x4  = __attribute__((ext_vector_type(4))) float;
typedef unsigned short u16;

__device__ __forceinline__ u16 f2bf(float f) {
  union { float f; unsigned u; } x; x.f = f;
  return (u16)((x.u + 0x7fffu + ((x.u >> 16) & 1u)) >> 16);
}
__device__ __forceinline__ float bf2f(u16 b) {
  union { unsigned u; float f; } x; x.u = ((unsigned)b) << 16;
  return x.f;
}

// ---------------- fp32 -> bf16 elementwise (float4 vectorized) ----------------
__global__ __launch_bounds__(256) void k_cvt(const float* __restrict__ src,
                                             u16* __restrict__ dst, int n4) {
  int i = blockIdx.x * blockDim.x + threadIdx.x;
  int stride = gridDim.x * blockDim.x;
  for (; i < n4; i += stride) {
    float4 v = ((const float4*)src)[i];
    ushort4 o;
    o.x = f2bf(v.x); o.y = f2bf(v.y); o.z = f2bf(v.z); o.w = f2bf(v.w);
    ((ushort4*)dst)[i] = o;
  }
}

// ------------- weight transpose + cvt: W[K][N] f32 -> WT[N][K] bf16 -----------
__global__ __launch_bounds__(256) void k_transpose(const float* __restrict__ W,
                                                   u16* __restrict__ WT,
                                                   int K, int N) {
  __shared__ float t[32][33];
  int bx = blockIdx.x * 32;
  int by = blockIdx.y * 32;
  int tx = threadIdx.x, ty = threadIdx.y;  // (32,8)
#pragma unroll
  for (int i = 0; i < 4; i++)
    t[ty + 8 * i][tx] = W[(size_t)(by + ty + 8 * i) * N + (bx + tx)];
  __syncthreads();
#pragma unroll
  for (int i = 0; i < 4; i++)
    WT[(size_t)(bx + ty + 8 * i) * K + (by + tx)] = f2bf(t[tx][ty + 8 * i]);
}

// ---------------- async global->LDS 16B staging ----------------
__device__ __forceinline__ void gl_lds16(const void* g, void* l) {
  __builtin_amdgcn_global_load_lds(
      (const __attribute__((address_space(1))) void*)g,
      (__attribute__((address_space(3))) void*)l, 16, 0, 0);
}

// ---------------- bijective XCD-aware block swizzle (T1, m204 form) -----------
__device__ __forceinline__ void xcd_swz(int& bx, int& by, int& bz) {
  const int nx = gridDim.x, ny = gridDim.y, nz = gridDim.z;
  const long nwg = (long)nx * ny * nz;
  if (nwg & 7) return;
  long lin = (long)bx + (long)nx * ((long)by + (long)ny * bz);
  const long q = nwg >> 3;
  const long nl = (lin & 7) * q + (lin >> 3);
  bx = (int)(nl % nx);
  long r2 = nl / nx;
  by = (int)(r2 % ny);
  bz = (int)(r2 / ny);
}

// =============== 256-row 8-wave gemm_bt: C = A[M][K] * BT[N][K]^T =============
// BNH=2: BN=256, 8-phase/2-K-tiles. BNH=1: BN=128, 4-phase/2-K-tiles.
// 8 waves (2M x 4N); per-wave 128 x (BNH*32). LDS: A dbuf 64K, B dbuf BNH*32K.
// Swizzle: slot ^= row&7 on global src + ds_read addr (both-sides, rule 21).
// FUSE: 0 none; 1 = exp(v) bf16 + row-sum partials; 2 = v *= finv[row].
#define SA(p, h, l, T) \
  gl_lds16(gA + (long)((h) * 128 + (l) * 64) * lda + (T) * 64, \
           dA + (p) * 32768 + (h) * 16384 + (l) * 8192)
#define SB(p, h, l, T) \
  gl_lds16(gB + (long)((h) * 128 + (l) * 64) * ldb + (T) * 64, \
           dB + (p) * (BNH * 16384) + (h) * 16384 + (l) * 8192)
#define RD_A(p, mh) { _Pragma("unroll") for (int m = 0; m < 4; m++) { \
    afr[m][0] = *(const bf16x8*)(lds + (p) * 32768 + aoffb + ((mh) * 64 + m * 16) * 128 + sb0); \
    afr[m][1] = *(const bf16x8*)(lds + (p) * 32768 + aoffb + ((mh) * 64 + m * 16) * 128 + sb1); } }
#define RD_B(p, nh, BF) { _Pragma("unroll") for (int n = 0; n < 2; n++) { \
    BF[n][0] = *(const bf16x8*)(lds + (p) * (BNH * 16384) + boffb + (((nh) * 2 + n) * 16) * 128 + sb0); \
    BF[n][1] = *(const bf16x8*)(lds + (p) * (BNH * 16384) + boffb + (((nh) * 2 + n) * 16) * 128 + sb1); } }
#define MFMA_QUAD(mh, nh, BF) { \
  _Pragma("unroll") for (int m = 0; m < 4; m++) \
  _Pragma("unroll") for (int n = 0; n < 2; n++) \
  _Pragma("unroll") for (int kk = 0; kk < 2; kk++) \
    acc[(mh) * 4 + m][(nh) * 2 + n] = __builtin_amdgcn_mfma_f32_16x16x32_bf16( \
        afr[m][kk], BF[n][kk], acc[(mh) * 4 + m][(nh) * 2 + n], 0, 0, 0); }
#define BAR_MFMA_OPEN() \
  __builtin_amdgcn_sched_barrier(0); \
  __builtin_amdgcn_s_barrier(); \
  asm volatile("s_waitcnt lgkmcnt(0)" ::: "memory"); \
  __builtin_amdgcn_sched_barrier(0); \
  __builtin_amdgcn_s_setprio(1)
#define PH_CLOSE() \
  __builtin_amdgcn_s_setprio(0); \
  __builtin_amdgcn_sched_barrier(0); \
  __builtin_amdgcn_s_barrier(); \
  __builtin_amdgcn_sched_barrier(0)
#define PH_CLOSE_VM(N) \
  __builtin_amdgcn_s_setprio(0); \
  asm volatile("s_waitcnt vmcnt(" #N ")" ::: "memory"); \
  __builtin_amdgcn_sched_barrier(0); \
  __builtin_amdgcn_s_barrier(); \
  __builtin_amdgcn_sched_barrier(0)

template <int BNH, int OUT_BF16, int BIAS_MODE, int FUSE>
__global__ __launch_bounds__(512, 2) void k_gemm256(
    const u16* __restrict__ A, const u16* __restrict__ BT,
    void* __restrict__ Cv, const float* __restrict__ bias,
    float* __restrict__ fpart, const float* __restrict__ finv,
    int K, int lda, int ldb, int ldc, long sA, long sB, long sC, float scale) {
  __shared__ __align__(16) char lds[65536 + BNH * 32768 + 1024];
  float* part = (float*)(lds + 65536 + BNH * 32768);

  int bxi = blockIdx.x, byi = blockIdx.y, bzi = blockIdx.z;
  xcd_swz(bxi, byi, bzi);
  const int tid = threadIdx.x, lane = tid & 63, wid = tid >> 6;
  const int wr = wid >> 2, wc = wid & 3;
  const int fr = lane & 15, kq = lane >> 4, fr7 = fr & 7;
  const int brow = byi * 256, bcol = bxi * (BNH * 128);
  const long z = bzi;

  if (FUSE == 2 && tid < 256) part[tid] = finv[z * 2048 + brow + tid];

  // staging: dest linear, src col pre-swizzled: col16 = (t&7) ^ ((t/8)&7)
  const int srow = tid >> 3;
  const int sslot = (tid & 7) ^ (srow & 7);
  const u16* gA = A + z * sA + (long)(brow + srow) * lda + sslot * 8;
  const u16* gB = BT + z * sB + (long)(bcol + srow) * ldb + sslot * 8;
  char* dA = lds + tid * 16;
  char* dB = lds + 65536 + tid * 16;

  // read-side bases; slot byte = ((kk*4+kq)^fr7)*16
  const int aoffb = (wr * 128 + fr) * 128;
  const int boffb = 65536 + (wc * (BNH * 32) + fr) * 128;
  const int sb0 = (kq ^ fr7) * 16;
  const int sb1 = ((4 + kq) ^ fr7) * 16;

  f32x4 acc[8][2 * BNH];
  const f32x4 zero = {0.f, 0.f, 0.f, 0.f};
#pragma unroll
  for (int m = 0; m < 8; m++)
#pragma unroll
    for (int n = 0; n < 2 * BNH; n++) acc[m][n] = zero;

  bf16x8 afr[4][2], bf0[2][2], bf1[2][2];
  const int iters = K >> 7;  // 2 K-tiles per iteration

  if (BNH == 2) {
    // prologue: tile0 full -> buf0, tile1 B -> buf1
    SA(0, 0, 0, 0); SA(0, 0, 1, 0); SA(0, 1, 0, 0); SA(0, 1, 1, 0);
    SB(0, 0, 0, 0); SB(0, 0, 1, 0); SB(0, 1, 0, 0); SB(0, 1, 1, 0);
    SB(1, 0, 0, 1); SB(1, 0, 1, 1); SB(1, 1, 0, 1); SB(1, 1, 1, 1);
    asm volatile("s_waitcnt vmcnt(4)" ::: "memory");
    __builtin_amdgcn_sched_barrier(0);
    __builtin_amdgcn_s_barrier();
    for (int i = 0; i < iters; i++) {
      const int t1 = 2 * i + 1, p0 = 2 * i + 2, p1 = 2 * i + 3;
      const bool more = (i + 1 < iters);
      RD_A(0, 0); RD_B(0, 0, bf0);
      SA(1, 0, 0, t1); SA(1, 0, 1, t1);
      BAR_MFMA_OPEN(); MFMA_QUAD(0, 0, bf0); PH_CLOSE();
      RD_B(0, 1, bf1);
      SA(1, 1, 0, t1); SA(1, 1, 1, t1);
      BAR_MFMA_OPEN(); MFMA_QUAD(0, 1, bf1); PH_CLOSE();
      RD_A(0, 1);
      if (more) { SB(0, 0, 0, p0); SB(0, 0, 1, p0); }
      BAR_MFMA_OPEN(); MFMA_QUAD(1, 0, bf0); PH_CLOSE();
      if (more) { SB(0, 1, 0, p0); SB(0, 1, 1, p0); }
      BAR_MFMA_OPEN(); MFMA_QUAD(1, 1, bf1);
      if (more) { PH_CLOSE_VM(4); } else { PH_CLOSE_VM(0); }
      RD_A(1, 0); RD_B(1, 0, bf0);
      if (more) { SA(0, 0, 0, p0); SA(0, 0, 1, p0); }
      BAR_MFMA_OPEN(); MFMA_QUAD(0, 0, bf0); PH_CLOSE();
      RD_B(1, 1, bf1);
      if (more) { SA(0, 1, 0, p0); SA(0, 1, 1, p0); }
      BAR_MFMA_OPEN(); MFMA_QUAD(0, 1, bf1); PH_CLOSE();
      RD_A(1, 1);
      if (more) { SB(1, 0, 0, p1); SB(1, 0, 1, p1); }
      BAR_MFMA_OPEN(); MFMA_QUAD(1, 0, bf0); PH_CLOSE();
      if (more) { SB(1, 1, 0, p1); SB(1, 1, 1, p1); }
      BAR_MFMA_OPEN(); MFMA_QUAD(1, 1, bf1);
      if (more) { PH_CLOSE_VM(4); } else { PH_CLOSE_VM(0); }
    }
  } else {
    // BNH=1: 4-phase. Loads/iter: A t1 (4), B p0 (2), A p0 (4), B p1 (2).
    // prologue: tile0 (A 4 + B 2) -> buf0, tile1 B (2) -> buf1
    SA(0, 0, 0, 0); SA(0, 0, 1, 0); SA(0, 1, 0, 0); SA(0, 1, 1, 0);
    SB(0, 0, 0, 0); SB(0, 0, 1, 0);
    SB(1, 0, 0, 1); SB(1, 0, 1, 1);
    asm volatile("s_waitcnt vmcnt(2)" ::: "memory");
    __builtin_amdgcn_sched_barrier(0);
    __builtin_amdgcn_s_barrier();
    for (int i = 0; i < iters; i++) {
      const int t1 = 2 * i + 1, p0 = 2 * i + 2, p1 = 2 * i + 3;
      const bool more = (i + 1 < iters);
      // phA: tile t0 quad(mh0); stage A[t1]h0
      RD_A(0, 0); RD_B(0, 0, bf0);
      SA(1, 0, 0, t1); SA(1, 0, 1, t1);
      BAR_MFMA_OPEN(); MFMA_QUAD(0, 0, bf0); PH_CLOSE();
      // phB: quad(mh1); stage A[t1]h1 then B[p0] (buf0-B reads done in phA)
      RD_A(0, 1);
      SA(1, 1, 0, t1); SA(1, 1, 1, t1);
      if (more) { SB(0, 0, 0, p0); SB(0, 0, 1, p0); }
      BAR_MFMA_OPEN(); MFMA_QUAD(1, 0, bf0);
      if (more) { PH_CLOSE_VM(2); } else { PH_CLOSE_VM(0); }
      // phC: tile t1 quad(mh0); stage A[p0]h0 (buf0-A reads done in phB)
      RD_A(1, 0); RD_B(1, 0, bf1);
      if (more) { SA(0, 0, 0, p0); SA(0, 0, 1, p0); }
      BAR_MFMA_OPEN(); MFMA_QUAD(0, 0, bf1); PH_CLOSE();
      // phD: quad(mh1); stage A[p0]h1 then B[p1] (buf1-B reads done in phC)
      RD_A(1, 1);
      if (more) { SA(0, 1, 0, p0); SA(0, 1, 1, p0);
                  SB(1, 0, 0, p1); SB(1, 0, 1, p1); }
      BAR_MFMA_OPEN(); MFMA_QUAD(1, 0, bf1);
      if (more) { PH_CLOSE_VM(2); } else { PH_CLOSE_VM(0); }
    }
  }

  if (FUSE == 1) {
    if (tid < 256) part[tid] = 0.f;
    __syncthreads();
  }

  // epilogue: D layout col=lane&15, row=kq*4+reg (m89-verified)
  const long zC = z * sC;
#pragma unroll
  for (int mi = 0; mi < 8; mi++) {
    const int r0 = brow + wr * 128 + mi * 16 + kq * 4;
    float s4[4] = {0.f, 0.f, 0.f, 0.f};
#pragma unroll
    for (int n = 0; n < 2 * BNH; n++) {
      const int c = bcol + wc * (BNH * 32) + n * 16 + fr;
#pragma unroll
      for (int r = 0; r < 4; r++) {
        float v = acc[mi][n][r] * scale;
        if (BIAS_MODE == 1) v += bias[c];
        if (BIAS_MODE == 2) v += bias[r0 + r];
        if (FUSE == 2) v *= part[r0 + r - brow];
        const long off = zC + (long)(r0 + r) * ldc + c;
        if (FUSE == 1) {
          float ef = __expf(fminf(v, 30.f));
          u16 eb = f2bf(ef);
          ((u16*)Cv)[off] = eb;
          s4[r] += bf2f(eb);  // sum the rounded values PV will read
        } else if (OUT_BF16) {
          ((u16*)Cv)[off] = f2bf(v);
        } else {
          ((float*)Cv)[off] = v;
        }
      }
    }
    if (FUSE == 1) {
#pragma unroll
      for (int r = 0; r < 4; r++) {
        float s = s4[r];
        s += __shfl_xor(s, 1); s += __shfl_xor(s, 2);
        s += __shfl_xor(s, 4); s += __shfl_xor(s, 8);
        if (fr == 0) atomicAdd(&part[r0 - brow + r], s);
      }
    }
  }
  if (FUSE == 1) {
    __syncthreads();
    if (tid < 256)
      fpart[((long)z * gridDim.x + bxi) * 2048 + brow + tid] = part[tid];
  }
}

// ---------- invsum: inv[i] = 1 / sum_j partials[j][i] (8 col-tile slots) ------
__global__ __launch_bounds__(256) void k_invsum(const float* __restrict__ part,
                                                float* __restrict__ inv) {
  int i = blockIdx.x * blockDim.x + threadIdx.x;
  long z = i >> 11;
  int row = i & 2047;
  float s = 0.f;
#pragma unroll
  for (int j = 0; j < 8; j++) s += part[(((z << 3) + j) << 11) + row];
  inv[i] = 1.f / s;
}

extern "C" void kernel_launch(void* const* d_in, const int* in_sizes, int n_in,
                              void* d_out, int out_size, void* d_ws, size_t ws_size,
                              hipStream_t stream) {
  (void)in_sizes; (void)n_in; (void)out_size;
  const float* in1 = (const float*)d_in[0];
  const float* in2 = (const float*)d_in[1];
  const float* Wq  = (const float*)d_in[2];
  const float* bq  = (const float*)d_in[3];
  const float* Wk  = (const float*)d_in[4];
  const float* bk  = (const float*)d_in[5];
  const float* Wv  = (const float*)d_in[6];
  const float* bv  = (const float*)d_in[7];
  float* out = (float*)d_out;

  const size_t MB = 1024ull * 1024ull;
  if (ws_size < 172 * MB) return;

  char* ws = (char*)d_ws;
  u16* A1   = (u16*)(ws + 0);
  u16* A2   = (u16*)(ws + 32 * MB);
  u16* S    = (u16*)(ws + 0);           // 8 batches x 8 MiB, reused per chunk
  u16* Q    = (u16*)(ws + 64 * MB);
  u16* Kb   = (u16*)(ws + 96 * MB);
  u16* VT   = (u16*)(ws + 128 * MB);
  u16* WqT  = (u16*)(ws + 160 * MB);
  u16* WkT  = (u16*)(ws + 160 * MB + 524288);
  u16* WvT  = (u16*)(ws + 160 * MB + 786432);
  float* Pt = (float*)(ws + 161 * MB);          // partials: 8 x 8 x 2048 f32
  float* Iv = (float*)(ws + 162 * MB + 262144); // invsum: 8 x 2048 f32

  k_cvt<<<2048, 256, 0, stream>>>(in1, A1, (int)((long)BATCH * NQ * DIMD / 4));
  k_cvt<<<2048, 256, 0, stream>>>(in2, A2, (int)((long)BATCH * NKV * LENL / 4));
  k_transpose<<<dim3(16, 16), dim3(32, 8), 0, stream>>>(Wq, WqT, DIMD, DIMD);
  k_transpose<<<dim3(16, 8),  dim3(32, 8), 0, stream>>>(Wk, WkT, LENL, DIMD);
  k_transpose<<<dim3(16, 8),  dim3(32, 8), 0, stream>>>(Wv, WvT, LENL, DIMD);

  // projections (256-tile 8-phase)
  k_gemm256<2, 1, 1, 0><<<dim3(2, 128, 1), 512, 0, stream>>>(
      A1, WqT, Q, bq, nullptr, nullptr, 512, 512, 512, 512, 0, 0, 0, 1.f);
  k_gemm256<2, 1, 1, 0><<<dim3(2, 128, 1), 512, 0, stream>>>(
      A2, WkT, Kb, bk, nullptr, nullptr, 256, 256, 256, 512, 0, 0, 0, 1.f);
  k_gemm256<2, 1, 2, 0><<<dim3(8, 2, 16), 512, 0, stream>>>(
      WvT, A2, VT, bv, nullptr, nullptr, 256, 256, 256, 2048,
      0L, (long)NKV * LENL, (long)DIMD * NKV, 1.f);

  const float qk_scale = 0.044194173824159216f;  // 1/sqrt(512)
  for (int c = 0; c < 2; c++) {
    const int zb = c * 8;
    // S = exp(Q K^T / sqrt(D)) (bf16, unnormalized) + row-sum partials
    k_gemm256<2, 1, 0, 1><<<dim3(8, 8, 8), 512, 0, stream>>>(
        Q + (long)zb * NQ * DIMD, Kb + (long)zb * NKV * DIMD, S, nullptr,
        Pt, nullptr, 512, 512, 512, 2048,
        (long)NQ * DIMD, (long)NKV * DIMD, (long)NQ * NKV, qk_scale);
    k_invsum<<<64, 256, 0, stream>>>(Pt, Iv);
    // out = (S~ @ VT^T) * invsum   (f32 out, BNH=1 -> 256 blocks)
    k_gemm256<1, 0, 0, 2><<<dim3(4, 8, 8), 512, 0, stream>>>(
        S, VT + (long)zb * DIMD * NKV, out + (long)zb * NQ * DIMD, nullptr,
        nullptr, Iv, 2048, 2048, 2048, 512,
        (long)NQ * NKV, (long)DIMD * NKV, (long)NQ * DIMD, 1.f);
  }
}

// Round 7
// 229.864 us; speedup vs baseline: 1.7425x; 1.2285x over previous
//
#include <hip/hip_runtime.h>

// CrossAttention B=16, N1=N2=2048, D=512, L=256 — algebraically restructured:
//   W' = Wk·Wq^T, bq' = bq·Wk^T           (tiny)
//   Q' = X1·W'^T + bq'                    [32768x256]
//   S~ = exp(Q'·X2^T / sqrt(512))         (bk-term cancels in softmax)
//   U  = S~·(X2^T)^T                      [32768x256]  (P·X2)
//   out= inv·(U·WvT^T) + bv               (bv exact since P rows sum to 1)
// Half the MFMA FLOPs of the direct form. GEMMs: proven 256-row 8-wave
// counted-vmcnt templates (BNH=2 8-phase / BNH=1 4-phase). Workspace ~195 MiB.

#define DIMD 512
#define LENL 256
#define BATCH 16
#define NQ 2048
#define NKV 2048

using bf16x8 = __attribute__((ext_vector_type(8))) __bf16;
using f32x4  = __attribute__((ext_vector_type(4))) float;
typedef unsigned short u16;

__device__ __forceinline__ u16 f2bf(float f) {
  union { float f; unsigned u; } x; x.f = f;
  return (u16)((x.u + 0x7fffu + ((x.u >> 16) & 1u)) >> 16);
}
__device__ __forceinline__ float bf2f(u16 b) {
  union { unsigned u; float f; } x; x.u = ((unsigned)b) << 16;
  return x.f;
}

// ---------------- fp32 -> bf16 elementwise (float4 vectorized) ----------------
__global__ __launch_bounds__(256) void k_cvt(const float* __restrict__ src,
                                             u16* __restrict__ dst, int n4) {
  int i = blockIdx.x * blockDim.x + threadIdx.x;
  int stride = gridDim.x * blockDim.x;
  for (; i < n4; i += stride) {
    float4 v = ((const float4*)src)[i];
    ushort4 o;
    o.x = f2bf(v.x); o.y = f2bf(v.y); o.z = f2bf(v.z); o.w = f2bf(v.w);
    ((ushort4*)dst)[i] = o;
  }
}

// ------------- weight transpose + cvt: W[K][N] f32 -> WT[N][K] bf16 -----------
__global__ __launch_bounds__(256) void k_transpose(const float* __restrict__ W,
                                                   u16* __restrict__ WT,
                                                   int K, int N) {
  __shared__ float t[32][33];
  int bx = blockIdx.x * 32;
  int by = blockIdx.y * 32;
  int tx = threadIdx.x, ty = threadIdx.y;  // (32,8)
#pragma unroll
  for (int i = 0; i < 4; i++)
    t[ty + 8 * i][tx] = W[(size_t)(by + ty + 8 * i) * N + (bx + tx)];
  __syncthreads();
#pragma unroll
  for (int i = 0; i < 4; i++)
    WT[(size_t)(bx + ty + 8 * i) * K + (by + tx)] = f2bf(t[tx][ty + 8 * i]);
}

// ------------- bf16 batched transpose: src[z][R][C] -> dst[z][C][R] -----------
__global__ __launch_bounds__(256) void k_transpose_bb(const u16* __restrict__ src,
                                                      u16* __restrict__ dst,
                                                      int R, int C,
                                                      long sS, long sD) {
  __shared__ u16 t[32][33];
  int bx = blockIdx.x * 32;  // C direction
  int by = blockIdx.y * 32;  // R direction
  long z = blockIdx.z;
  const u16* s = src + z * sS;
  u16* d = dst + z * sD;
  int tx = threadIdx.x, ty = threadIdx.y;  // (32,8)
#pragma unroll
  for (int i = 0; i < 4; i++)
    t[ty + 8 * i][tx] = s[(size_t)(by + ty + 8 * i) * C + (bx + tx)];
  __syncthreads();
#pragma unroll
  for (int i = 0; i < 4; i++)
    d[(size_t)(bx + ty + 8 * i) * R + (by + tx)] = t[tx][ty + 8 * i];
}

// ------------- bq'[n] = sum_o bq[o] * Wk[n][o]  (256 outputs, 1 block) -------
__global__ __launch_bounds__(256) void k_bqp(const float* __restrict__ bq,
                                             const float* __restrict__ Wk,
                                             float* __restrict__ bqp) {
  int n = threadIdx.x;
  float s = 0.f;
  for (int o = 0; o < 512; o += 4) {
    float4 w = *(const float4*)&Wk[(size_t)n * 512 + o];
    float4 b = *(const float4*)&bq[o];
    s += w.x * b.x + w.y * b.y + w.z * b.z + w.w * b.w;
  }
  bqp[n] = s;
}

// ---------------- async global->LDS 16B staging ----------------
__device__ __forceinline__ void gl_lds16(const void* g, void* l) {
  __builtin_amdgcn_global_load_lds(
      (const __attribute__((address_space(1))) void*)g,
      (__attribute__((address_space(3))) void*)l, 16, 0, 0);
}

// ---------------- bijective XCD-aware block swizzle (T1, m204 form) -----------
__device__ __forceinline__ void xcd_swz(int& bx, int& by, int& bz) {
  const int nx = gridDim.x, ny = gridDim.y, nz = gridDim.z;
  const long nwg = (long)nx * ny * nz;
  if (nwg & 7) return;
  long lin = (long)bx + (long)nx * ((long)by + (long)ny * bz);
  const long q = nwg >> 3;
  const long nl = (lin & 7) * q + (lin >> 3);
  bx = (int)(nl % nx);
  long r2 = nl / nx;
  by = (int)(r2 % ny);
  bz = (int)(r2 / ny);
}

// =============== 256-row 8-wave gemm_bt: C = A[M][K] * BT[N][K]^T =============
// BNH=2: BN=256, 8-phase/2-K-tiles. BNH=1: BN=128, 4-phase/2-K-tiles.
// Swizzle: slot ^= row&7 on global src + ds_read addr (both-sides, rule 21).
// FUSE: 0 none; 1 = exp(v) bf16 + row-sum partials; 2 = v *= finv[row];
//       3 = v = v*finv[row] + bias[col].
#define SA(p, h, l, T) \
  gl_lds16(gA + (long)((h) * 128 + (l) * 64) * lda + (T) * 64, \
           dA + (p) * 32768 + (h) * 16384 + (l) * 8192)
#define SB(p, h, l, T) \
  gl_lds16(gB + (long)((h) * 128 + (l) * 64) * ldb + (T) * 64, \
           dB + (p) * (BNH * 16384) + (h) * 16384 + (l) * 8192)
#define RD_A(p, mh) { _Pragma("unroll") for (int m = 0; m < 4; m++) { \
    afr[m][0] = *(const bf16x8*)(lds + (p) * 32768 + aoffb + ((mh) * 64 + m * 16) * 128 + sb0); \
    afr[m][1] = *(const bf16x8*)(lds + (p) * 32768 + aoffb + ((mh) * 64 + m * 16) * 128 + sb1); } }
#define RD_B(p, nh, BF) { _Pragma("unroll") for (int n = 0; n < 2; n++) { \
    BF[n][0] = *(const bf16x8*)(lds + (p) * (BNH * 16384) + boffb + (((nh) * 2 + n) * 16) * 128 + sb0); \
    BF[n][1] = *(const bf16x8*)(lds + (p) * (BNH * 16384) + boffb + (((nh) * 2 + n) * 16) * 128 + sb1); } }
#define MFMA_QUAD(mh, nh, BF) { \
  _Pragma("unroll") for (int m = 0; m < 4; m++) \
  _Pragma("unroll") for (int n = 0; n < 2; n++) \
  _Pragma("unroll") for (int kk = 0; kk < 2; kk++) \
    acc[(mh) * 4 + m][(nh) * 2 + n] = __builtin_amdgcn_mfma_f32_16x16x32_bf16( \
        afr[m][kk], BF[n][kk], acc[(mh) * 4 + m][(nh) * 2 + n], 0, 0, 0); }
#define BAR_MFMA_OPEN() \
  __builtin_amdgcn_sched_barrier(0); \
  __builtin_amdgcn_s_barrier(); \
  asm volatile("s_waitcnt lgkmcnt(0)" ::: "memory"); \
  __builtin_amdgcn_sched_barrier(0); \
  __builtin_amdgcn_s_setprio(1)
#define PH_CLOSE() \
  __builtin_amdgcn_s_setprio(0); \
  __builtin_amdgcn_sched_barrier(0); \
  __builtin_amdgcn_s_barrier(); \
  __builtin_amdgcn_sched_barrier(0)
#define PH_CLOSE_VM(N) \
  __builtin_amdgcn_s_setprio(0); \
  asm volatile("s_waitcnt vmcnt(" #N ")" ::: "memory"); \
  __builtin_amdgcn_sched_barrier(0); \
  __builtin_amdgcn_s_barrier(); \
  __builtin_amdgcn_sched_barrier(0)

template <int BNH, int OUT_BF16, int BIAS_MODE, int FUSE>
__global__ __launch_bounds__(512, 2) void k_gemm256(
    const u16* __restrict__ A, const u16* __restrict__ BT,
    void* __restrict__ Cv, const float* __restrict__ bias,
    float* __restrict__ fpart, const float* __restrict__ finv,
    int K, int lda, int ldb, int ldc, long sA, long sB, long sC, float scale) {
  __shared__ __align__(16) char lds[65536 + BNH * 32768 + 1024];
  float* part = (float*)(lds + 65536 + BNH * 32768);

  int bxi = blockIdx.x, byi = blockIdx.y, bzi = blockIdx.z;
  xcd_swz(bxi, byi, bzi);
  const int tid = threadIdx.x, lane = tid & 63, wid = tid >> 6;
  const int wr = wid >> 2, wc = wid & 3;
  const int fr = lane & 15, kq = lane >> 4, fr7 = fr & 7;
  const int brow = byi * 256, bcol = bxi * (BNH * 128);
  const long z = bzi;

  if ((FUSE == 2 || FUSE == 3) && tid < 256)
    part[tid] = finv[z * 2048 + brow + tid];

  // staging: dest linear, src col pre-swizzled: col16 = (t&7) ^ ((t/8)&7)
  const int srow = tid >> 3;
  const int sslot = (tid & 7) ^ (srow & 7);
  const u16* gA = A + z * sA + (long)(brow + srow) * lda + sslot * 8;
  const u16* gB = BT + z * sB + (long)(bcol + srow) * ldb + sslot * 8;
  char* dA = lds + tid * 16;
  char* dB = lds + 65536 + tid * 16;

  // read-side bases; slot byte = ((kk*4+kq)^fr7)*16
  const int aoffb = (wr * 128 + fr) * 128;
  const int boffb = 65536 + (wc * (BNH * 32) + fr) * 128;
  const int sb0 = (kq ^ fr7) * 16;
  const int sb1 = ((4 + kq) ^ fr7) * 16;

  f32x4 acc[8][2 * BNH];
  const f32x4 zero = {0.f, 0.f, 0.f, 0.f};
#pragma unroll
  for (int m = 0; m < 8; m++)
#pragma unroll
    for (int n = 0; n < 2 * BNH; n++) acc[m][n] = zero;

  bf16x8 afr[4][2], bf0[2][2], bf1[2][2];
  const int iters = K >> 7;  // 2 K-tiles per iteration

  if (BNH == 2) {
    // prologue: tile0 full -> buf0, tile1 B -> buf1
    SA(0, 0, 0, 0); SA(0, 0, 1, 0); SA(0, 1, 0, 0); SA(0, 1, 1, 0);
    SB(0, 0, 0, 0); SB(0, 0, 1, 0); SB(0, 1, 0, 0); SB(0, 1, 1, 0);
    SB(1, 0, 0, 1); SB(1, 0, 1, 1); SB(1, 1, 0, 1); SB(1, 1, 1, 1);
    asm volatile("s_waitcnt vmcnt(4)" ::: "memory");
    __builtin_amdgcn_sched_barrier(0);
    __builtin_amdgcn_s_barrier();
    for (int i = 0; i < iters; i++) {
      const int t1 = 2 * i + 1, p0 = 2 * i + 2, p1 = 2 * i + 3;
      const bool more = (i + 1 < iters);
      RD_A(0, 0); RD_B(0, 0, bf0);
      SA(1, 0, 0, t1); SA(1, 0, 1, t1);
      BAR_MFMA_OPEN(); MFMA_QUAD(0, 0, bf0); PH_CLOSE();
      RD_B(0, 1, bf1);
      SA(1, 1, 0, t1); SA(1, 1, 1, t1);
      BAR_MFMA_OPEN(); MFMA_QUAD(0, 1, bf1); PH_CLOSE();
      RD_A(0, 1);
      if (more) { SB(0, 0, 0, p0); SB(0, 0, 1, p0); }
      BAR_MFMA_OPEN(); MFMA_QUAD(1, 0, bf0); PH_CLOSE();
      if (more) { SB(0, 1, 0, p0); SB(0, 1, 1, p0); }
      BAR_MFMA_OPEN(); MFMA_QUAD(1, 1, bf1);
      if (more) { PH_CLOSE_VM(4); } else { PH_CLOSE_VM(0); }
      RD_A(1, 0); RD_B(1, 0, bf0);
      if (more) { SA(0, 0, 0, p0); SA(0, 0, 1, p0); }
      BAR_MFMA_OPEN(); MFMA_QUAD(0, 0, bf0); PH_CLOSE();
      RD_B(1, 1, bf1);
      if (more) { SA(0, 1, 0, p0); SA(0, 1, 1, p0); }
      BAR_MFMA_OPEN(); MFMA_QUAD(0, 1, bf1); PH_CLOSE();
      RD_A(1, 1);
      if (more) { SB(1, 0, 0, p1); SB(1, 0, 1, p1); }
      BAR_MFMA_OPEN(); MFMA_QUAD(1, 0, bf0); PH_CLOSE();
      if (more) { SB(1, 1, 0, p1); SB(1, 1, 1, p1); }
      BAR_MFMA_OPEN(); MFMA_QUAD(1, 1, bf1);
      if (more) { PH_CLOSE_VM(4); } else { PH_CLOSE_VM(0); }
    }
  } else {
    // BNH=1: 4-phase. prologue: tile0 (A 4 + B 2) -> buf0, tile1 B (2) -> buf1
    SA(0, 0, 0, 0); SA(0, 0, 1, 0); SA(0, 1, 0, 0); SA(0, 1, 1, 0);
    SB(0, 0, 0, 0); SB(0, 0, 1, 0);
    SB(1, 0, 0, 1); SB(1, 0, 1, 1);
    asm volatile("s_waitcnt vmcnt(2)" ::: "memory");
    __builtin_amdgcn_sched_barrier(0);
    __builtin_amdgcn_s_barrier();
    for (int i = 0; i < iters; i++) {
      const int t1 = 2 * i + 1, p0 = 2 * i + 2, p1 = 2 * i + 3;
      const bool more = (i + 1 < iters);
      RD_A(0, 0); RD_B(0, 0, bf0);
      SA(1, 0, 0, t1); SA(1, 0, 1, t1);
      BAR_MFMA_OPEN(); MFMA_QUAD(0, 0, bf0); PH_CLOSE();
      RD_A(0, 1);
      SA(1, 1, 0, t1); SA(1, 1, 1, t1);
      if (more) { SB(0, 0, 0, p0); SB(0, 0, 1, p0); }
      BAR_MFMA_OPEN(); MFMA_QUAD(1, 0, bf0);
      if (more) { PH_CLOSE_VM(2); } else { PH_CLOSE_VM(0); }
      RD_A(1, 0); RD_B(1, 0, bf1);
      if (more) { SA(0, 0, 0, p0); SA(0, 0, 1, p0); }
      BAR_MFMA_OPEN(); MFMA_QUAD(0, 0, bf1); PH_CLOSE();
      RD_A(1, 1);
      if (more) { SA(0, 1, 0, p0); SA(0, 1, 1, p0);
                  SB(1, 0, 0, p1); SB(1, 0, 1, p1); }
      BAR_MFMA_OPEN(); MFMA_QUAD(1, 0, bf1);
      if (more) { PH_CLOSE_VM(2); } else { PH_CLOSE_VM(0); }
    }
  }

  if (FUSE == 1) {
    if (tid < 256) part[tid] = 0.f;
    __syncthreads();
  }

  // epilogue: D layout col=lane&15, row=kq*4+reg (m89-verified)
  const long zC = z * sC;
#pragma unroll
  for (int mi = 0; mi < 8; mi++) {
    const int r0 = brow + wr * 128 + mi * 16 + kq * 4;
    float s4[4] = {0.f, 0.f, 0.f, 0.f};
#pragma unroll
    for (int n = 0; n < 2 * BNH; n++) {
      const int c = bcol + wc * (BNH * 32) + n * 16 + fr;
#pragma unroll
      for (int r = 0; r < 4; r++) {
        float v = acc[mi][n][r] * scale;
        if (BIAS_MODE == 1) v += bias[c];
        if (BIAS_MODE == 2) v += bias[r0 + r];
        if (FUSE == 2) v *= part[r0 + r - brow];
        if (FUSE == 3) v = v * part[r0 + r - brow] + bias[c];
        const long off = zC + (long)(r0 + r) * ldc + c;
        if (FUSE == 1) {
          float ef = __expf(fminf(v, 30.f));
          u16 eb = f2bf(ef);
          ((u16*)Cv)[off] = eb;
          s4[r] += bf2f(eb);  // sum the rounded values the next GEMM reads
        } else if (OUT_BF16) {
          ((u16*)Cv)[off] = f2bf(v);
        } else {
          ((float*)Cv)[off] = v;
        }
      }
    }
    if (FUSE == 1) {
#pragma unroll
      for (int r = 0; r < 4; r++) {
        float s = s4[r];
        s += __shfl_xor(s, 1); s += __shfl_xor(s, 2);
        s += __shfl_xor(s, 4); s += __shfl_xor(s, 8);
        if (fr == 0) atomicAdd(&part[r0 - brow + r], s);
      }
    }
  }
  if (FUSE == 1) {
    __syncthreads();
    if (tid < 256)
      fpart[((long)z * gridDim.x + bxi) * 2048 + brow + tid] = part[tid];
  }
}

// ---------- invsum: inv[i] = 1 / sum_j partials[z][j][row] (8 col-tiles) ------
__global__ __launch_bounds__(256) void k_invsum(const float* __restrict__ part,
                                                float* __restrict__ inv) {
  int i = blockIdx.x * blockDim.x + threadIdx.x;  // 0..32767
  long z = i >> 11;
  int row = i & 2047;
  float s = 0.f;
#pragma unroll
  for (int j = 0; j < 8; j++) s += part[(((z << 3) + j) << 11) + row];
  inv[i] = 1.f / s;
}

extern "C" void kernel_launch(void* const* d_in, const int* in_sizes, int n_in,
                              void* d_out, int out_size, void* d_ws, size_t ws_size,
                              hipStream_t stream) {
  (void)in_sizes; (void)n_in; (void)out_size;
  const float* in1 = (const float*)d_in[0];
  const float* in2 = (const float*)d_in[1];
  const float* Wq  = (const float*)d_in[2];
  const float* bq  = (const float*)d_in[3];
  const float* Wk  = (const float*)d_in[4];
  const float* Wv  = (const float*)d_in[6];
  const float* bv  = (const float*)d_in[7];
  float* out = (float*)d_out;

  const size_t MB = 1024ull * 1024ull;
  if (ws_size < 204 * MB) return;  // need ~194.5 MiB (proven ws >= 225 MiB)

  // layout (byte offsets). A1 [0,32M) is dead before S~ overwrites [0,128M).
  char* ws = (char*)d_ws;
  u16* A1   = (u16*)(ws + 0);               // [32768][512] bf16 X1
  u16* S    = (u16*)(ws + 0);               // [16][2048][2048] bf16 scores
  u16* A2   = (u16*)(ws + 134217728);       // [32768][256] bf16 X2
  u16* Qp   = (u16*)(ws + 150994944);       // [32768][256] bf16 Q'
  u16* TX2  = (u16*)(ws + 167772160);       // [16][256][2048] bf16 X2^T
  u16* U    = (u16*)(ws + 184549376);       // [32768][256] bf16 P~·X2
  u16* Wqb  = (u16*)(ws + 201326592);       // [512][512]
  u16* Wkb  = (u16*)(ws + 201850880);       // [256][512]
  u16* WvT  = (u16*)(ws + 202113024);       // [512][256]
  u16* WT1  = (u16*)(ws + 202375168);       // [256][512]  Wk·Wq^T
  float* bqp = (float*)(ws + 202637312);    // [256]
  float* Pt  = (float*)(ws + 202638336);    // [16][8][2048] f32 partial sums
  float* Iv  = (float*)(ws + 203686912);    // [32768] f32 inv row sums

  // 1) bf16 conversions
  k_cvt<<<2048, 256, 0, stream>>>(in1, A1, 32768 * 512 / 4);
  k_cvt<<<2048, 256, 0, stream>>>(in2, A2, 32768 * 256 / 4);
  k_cvt<<<256, 256, 0, stream>>>(Wq, Wqb, 512 * 512 / 4);
  k_cvt<<<128, 256, 0, stream>>>(Wk, Wkb, 256 * 512 / 4);
  // 2) transposes
  k_transpose<<<dim3(16, 8), dim3(32, 8), 0, stream>>>(Wv, WvT, LENL, DIMD);
  k_transpose_bb<<<dim3(8, 64, 16), dim3(32, 8), 0, stream>>>(
      A2, TX2, NKV, LENL, (long)NKV * LENL, (long)LENL * NKV);
  // 3) W' = Wk·Wq^T  (M=256, N=512, K=512) and bq' = bq·Wk^T
  k_gemm256<2, 1, 0, 0><<<dim3(2, 1, 1), 512, 0, stream>>>(
      Wkb, Wqb, WT1, nullptr, nullptr, nullptr,
      512, 512, 512, 512, 0, 0, 0, 1.f);
  k_bqp<<<1, 256, 0, stream>>>(bq, Wk, bqp);
  // 4) Q' = X1·W'^T + bq'  (M=32768, N=256, K=512; BNH=1 -> 256 blocks)
  k_gemm256<1, 1, 1, 0><<<dim3(2, 128, 1), 512, 0, stream>>>(
      A1, WT1, Qp, bqp, nullptr, nullptr,
      512, 512, 512, 256, 0, 0, 0, 1.f);
  // 5) S~ = exp(Q'·X2^T / sqrt(512)) + row-sum partials  (K=256, batched 16)
  const float qk_scale = 0.044194173824159216f;  // 1/sqrt(512)
  k_gemm256<2, 1, 0, 1><<<dim3(8, 8, 16), 512, 0, stream>>>(
      Qp, A2, S, nullptr, Pt, nullptr, 256, 256, 256, 2048,
      (long)NQ * LENL, (long)NKV * LENL, (long)NQ * NKV, qk_scale);
  // 6) inverse row sums
  k_invsum<<<128, 256, 0, stream>>>(Pt, Iv);
  // 7) U = S~·(X2^T)^T  (M=2048, N=256, K=2048, batched; BNH=1 -> 256 blocks)
  k_gemm256<1, 1, 0, 0><<<dim3(2, 8, 16), 512, 0, stream>>>(
      S, TX2, U, nullptr, nullptr, nullptr, 2048, 2048, 2048, 256,
      (long)NQ * NKV, (long)LENL * NKV, (long)NQ * LENL, 1.f);
  // 8) out = inv·(U·WvT^T) + bv  (M=32768, N=512, K=256, f32 out)
  k_gemm256<2, 0, 0, 3><<<dim3(2, 128, 1), 512, 0, stream>>>(
      U, WvT, out, bv, nullptr, Iv, 256, 256, 256, 512, 0, 0, 0, 1.f);
}